// Round 1
// 237.735 us; speedup vs baseline: 1.0428x; 1.0428x over previous
//
#include <hip/hip_runtime.h>
#include <math.h>

#define NV 8
#define NC 14
#define NH 480
#define NW 640
#define HW (NH * NW)
#define NPIX (NV * HW)
#define OC 15
#define BLK 256
#define PPT 2                 // pixels per thread
#define PIXB (BLK * PPT)      // 512 pixels per block

#define LOG2E 1.44269504088896340736f
#define LN2   0.69314718055994530942f

typedef float f2 __attribute__((ext_vector_type(2)));
typedef float f4 __attribute__((ext_vector_type(4)));

// ---- single-instruction HW math (v_exp_f32 / v_log_f32 / v_rcp_f32 / v_rsq_f32) ----
__device__ __forceinline__ float fexp2_(float x) {
#if __has_builtin(__builtin_amdgcn_exp2f)
    return __builtin_amdgcn_exp2f(x);
#else
    return exp2f(x);
#endif
}
__device__ __forceinline__ float flog2_(float x) {
#if __has_builtin(__builtin_amdgcn_logf)
    return __builtin_amdgcn_logf(x);
#else
    return log2f(x);
#endif
}
__device__ __forceinline__ float frcp_(float x) {
#if __has_builtin(__builtin_amdgcn_rcpf)
    return __builtin_amdgcn_rcpf(x);
#else
    return 1.0f / x;
#endif
}
__device__ __forceinline__ float frsq_(float x) {
#if __has_builtin(__builtin_amdgcn_rsqf)
    return __builtin_amdgcn_rsqf(x);
#else
    return rsqrtf(x);
#endif
}

__device__ __forceinline__ float sigmoidf_(float x) {
    return frcp_(1.0f + fexp2_(-x * LOG2E));
}
__device__ __forceinline__ float softplusf_(float x) {
    return fmaxf(x, 0.0f) + LN2 * flog2_(1.0f + fexp2_(-fabsf(x) * LOG2E));
}

__global__ __launch_bounds__(BLK) void DecoderSplatting_kernel(
    const float* __restrict__ raw,   // (1, V, C, H, W)
    const float* __restrict__ ext,   // (1, V, 4, 4)
    const float* __restrict__ intr,  // (1, V, 3, 3)
    float* __restrict__ out)         // (V, H, W, 15)
{
    __shared__ __align__(16) float sout[PIXB * OC];   // 30720 B

    const int tid = threadIdx.x;
    // v is block-uniform: HW % PIXB == 0 (307200/512=600), block never crosses a view.
    const int blockStart = blockIdx.x * PIXB;
    const int v = blockStart / HW;                // uniform -> SGPR
    const int pinBase = blockStart - v * HW;
    const int pin0 = pinBase + tid * PPT;         // first pixel of this thread's pair

    // ---- per-view constants (uniform -> s_load) ----
    const float* E = ext + v * 16;
    const float* K = intr + v * 9;
    const float a00 = K[0], a01 = K[1], a02 = K[2];
    const float a10 = K[3], a11 = K[4], a12 = K[5];
    const float a20 = K[6], a21 = K[7], a22 = K[8];
    const float c00 = a11 * a22 - a12 * a21;
    const float c01 = a12 * a20 - a10 * a22;
    const float c02 = a10 * a21 - a11 * a20;
    const float invdet = 1.0f / (a00 * c00 + a01 * c01 + a02 * c02);
    const float i00 = c00 * invdet;
    const float i01 = (a02 * a21 - a01 * a22) * invdet;
    const float i02 = (a01 * a12 - a02 * a11) * invdet;
    const float i10 = c01 * invdet;
    const float i11 = (a00 * a22 - a02 * a20) * invdet;
    const float i12 = (a02 * a10 - a00 * a12) * invdet;
    const float i20 = c02 * invdet;
    const float i21 = (a01 * a20 - a00 * a21) * invdet;
    const float i22 = (a00 * a11 - a01 * a10) * invdet;
    const float mult = (a00 + a11 - a01 - a10) / (a00 * a11 - a01 * a10);

    const float E0 = E[0],  E1 = E[1],  E2 = E[2],  E3 = E[3];
    const float E4 = E[4],  E5 = E[5],  E6 = E[6],  E7 = E[7];
    const float E8 = E[8],  E9 = E[9],  E10 = E[10], E11 = E[11];
    const float E12 = E[12], E13 = E[13], E14 = E[14], E15 = E[15];

    // ---- load 14 channels x 2 pixels as float2 (8 B/lane, coalesced per plane) ----
    const f2* rp2 = (const f2*)(raw + (size_t)v * NC * HW + pin0);
    f2 ch2[NC];
#pragma unroll
    for (int c = 0; c < NC; ++c)
        ch2[c] = __builtin_nontemporal_load(&rp2[(size_t)c * (HW / 2)]);

    // ---- per-pixel pipeline (inlined twice) ----
    auto compute_store = [&](const float ch[NC], int pin) {
        const int py = pin / NW;
        const int px = pin - py * NW;

        // ray direction
        const float cx = (float)px + sigmoidf_(ch[12]) - 0.5f;
        const float cy = (float)py + sigmoidf_(ch[13]) - 0.5f;
        float dx = i00 * cx + i01 * cy + i02;
        float dy = i10 * cx + i11 * cy + i12;
        float dz = i20 * cx + i21 * cy + i22;
        const float dinv = frsq_(dx * dx + dy * dy + dz * dz);
        dx *= dinv; dy *= dinv; dz *= dinv;

        // depth and means (4 components: homogeneous row included)
        const float depth = frcp_(sigmoidf_(ch[3]) * 19.95f + 0.05f);
        const float m0 = E3  + (E0  * dx + E1  * dy + E2  * dz) * depth;
        const float m1 = E7  + (E4  * dx + E5  * dy + E6  * dz) * depth;
        const float m2 = E11 + (E8  * dx + E9  * dy + E10 * dz) * depth;
        const float m3 = E15 + (E12 * dx + E13 * dy + E14 * dz) * depth;

        // rgb / opacity / scales
        const float r0 = softplusf_(ch[0]);
        const float r1 = softplusf_(ch[1]);
        const float r2 = softplusf_(ch[2]);
        const float op = sigmoidf_(ch[4]);
        const float s0 = softplusf_(ch[5]) * mult;
        const float s1 = softplusf_(ch[6]) * mult;
        const float s2 = softplusf_(ch[7]) * mult;

        // rotation: single rsq normalization == ref's divide+renorm (diff O(1e-6) << thr)
        float qx = ch[8], qy = ch[9], qz = ch[10], qw = ch[11];
        const float qinv = frsq_(qx * qx + qy * qy + qz * qz + qw * qw);
        qx *= qinv; qy *= qinv; qz *= qinv; qw *= qinv;

        const float b00 = 1.0f - 2.0f * (qy * qy + qz * qz);
        const float b01 = 2.0f * (qx * qy - qz * qw);
        const float b02 = 2.0f * (qx * qz + qy * qw);
        const float b10 = 2.0f * (qx * qy + qz * qw);
        const float b11 = 1.0f - 2.0f * (qx * qx + qz * qz);
        const float b12 = 2.0f * (qy * qz - qx * qw);
        const float b20 = 2.0f * (qx * qz - qy * qw);
        const float b21 = 2.0f * (qy * qz + qx * qw);
        const float b22 = 1.0f - 2.0f * (qx * qx + qy * qy);

        // M = ext[:3,:3] @ B
        const float M00 = E0 * b00 + E1 * b10 + E2 * b20;
        const float M01 = E0 * b01 + E1 * b11 + E2 * b21;
        const float M02 = E0 * b02 + E1 * b12 + E2 * b22;
        const float M10 = E4 * b00 + E5 * b10 + E6 * b20;
        const float M11 = E4 * b01 + E5 * b11 + E6 * b21;
        const float M12 = E4 * b02 + E5 * b12 + E6 * b22;
        const float M20 = E8 * b00 + E9 * b10 + E10 * b20;
        const float M21 = E8 * b01 + E9 * b11 + E10 * b21;
        const float M22 = E8 * b02 + E9 * b12 + E10 * b22;

        // mat -> quat (wxyz), first-occurrence argmax([M00,M11,M22,tr])
        const float tr = M00 + M11 + M22;
        int choice = 0;
        float best = M00;
        if (M11 > best) { best = M11; choice = 1; }
        if (M22 > best) { best = M22; choice = 2; }
        if (tr  > best) { best = tr;  choice = 3; }

        float w0, w1, w2, w3;
        if (choice == 0) {
            w0 = M21 - M12;
            w1 = 1.0f + M00 - M11 - M22;
            w2 = M01 + M10;
            w3 = M02 + M20;
        } else if (choice == 1) {
            w0 = M02 - M20;
            w1 = M01 + M10;
            w2 = 1.0f + M11 - M00 - M22;
            w3 = M12 + M21;
        } else if (choice == 2) {
            w0 = M10 - M01;
            w1 = M02 + M20;
            w2 = M12 + M21;
            w3 = 1.0f + M22 - M00 - M11;
        } else {
            w0 = 1.0f + tr;
            w1 = M21 - M12;
            w2 = M02 - M20;
            w3 = M10 - M01;
        }
        const float winv = frsq_(w0 * w0 + w1 * w1 + w2 * w2 + w3 * w3);
        w0 *= winv; w1 *= winv; w2 *= winv; w3 *= winv;

        // stage 15 outputs in LDS (stride 15; 4-way write aliasing accepted,
        // float4 readout below stays contiguous/conflict-free)
        float* so = sout + (size_t)(pin - pinBase) * OC;
        so[0]  = m0;  so[1]  = m1;  so[2]  = m2;  so[3]  = m3;
        so[4]  = r0;  so[5]  = r1;  so[6]  = r2;
        so[7]  = op;
        so[8]  = s0;  so[9]  = s1;  so[10] = s2;
        so[11] = w0;  so[12] = w1;  so[13] = w2;  so[14] = w3;
    };

    {
        float ch[NC];
#pragma unroll
        for (int c = 0; c < NC; ++c) ch[c] = ch2[c].x;
        compute_store(ch, pin0);
#pragma unroll
        for (int c = 0; c < NC; ++c) ch[c] = ch2[c].y;
        compute_store(ch, pin0 + 1);
    }

    __syncthreads();

    // ---- coalesced nontemporal float4 writeback: 512*15 floats = 1920 float4 ----
    const f4* s4 = (const f4*)sout;
    f4* o4 = (f4*)(out + (size_t)blockStart * OC);
#pragma unroll
    for (int j = 0; j < (PIXB * OC) / 4; j += BLK) {
        const int idx = j + tid;
        if (idx < (PIXB * OC) / 4)
            __builtin_nontemporal_store(s4[idx], &o4[idx]);
    }
}

extern "C" void kernel_launch(void* const* d_in, const int* in_sizes, int n_in,
                              void* d_out, int out_size, void* d_ws, size_t ws_size,
                              hipStream_t stream) {
    const float* raw  = (const float*)d_in[0];
    const float* ext  = (const float*)d_in[1];
    const float* intr = (const float*)d_in[2];
    float* out = (float*)d_out;

    dim3 grid(NPIX / PIXB);   // 2457600 / 512 = 4800 blocks
    dim3 block(BLK);
    DecoderSplatting_kernel<<<grid, block, 0, stream>>>(raw, ext, intr, out);
}